// Round 1
// baseline (1162.232 us; speedup 1.0000x reference)
//
#include <hip/hip_runtime.h>

// ---------------- problem constants ----------------
#define B_    16
#define M_    128
#define N_    128
#define DIN   12
#define D_    64
#define H_    128
#define MODES 16
#define NL    4
#define NPIX  262144       // B*M*N
#define NROW  2048         // B*M == B*N

// ---------------- vector types ----------------
typedef float  f32x2 __attribute__((ext_vector_type(2)));
typedef float  f32x4 __attribute__((ext_vector_type(4)));
typedef short  s16x8 __attribute__((ext_vector_type(8)));
typedef unsigned int u32x4 __attribute__((ext_vector_type(4)));

// ---------------- workspace layout (float elements) ----------------
#define OFF_X   0L           // [B,M,N,64] f32     16777216
#define OFF_XS  16777216L    // [B,M,N,64] f32     16777216
#define OFF_TRE 33554432L    // [16][2048][64]      2097152
#define OFF_TIM 35651584L
#define OFF_PRE 37748736L
#define OFF_PIM 39845888L
#define OFF_BF  41943040L    // fwd basis  [n=128][kp=32]
#define OFF_BI  41947136L    // inv basis  [n=128][kp=32]
#define OFF_U   41951232L    // u[4][128]
#define OFF_DD  41951744L    // d[4]
#define OFF_WB  41951760L    // bf16 weights region (byte-addressed below); 16B aligned
#define WS_NEEDED_BYTES 168003648L

__device__ __forceinline__ unsigned short f2bf(float f){
    unsigned int u = __float_as_uint(f);
    u += 0x7fffu + ((u >> 16) & 1u);
    return (unsigned short)(u >> 16);
}
__device__ __forceinline__ float bf2f(unsigned short s){
    return __uint_as_float(((unsigned int)s) << 16);
}

// ============ init: basis tables + collapsed output head ============
__global__ void k_init(const float* __restrict__ out_w1, const float* __restrict__ out_b1,
                       const float* __restrict__ out_w2, const float* __restrict__ out_b2,
                       const float* __restrict__ fc_w2, const float* __restrict__ fc_b2,
                       float* __restrict__ ws){
    __shared__ float v_s[64];
    __shared__ float c_s;
    int t = threadIdx.x;
    if (t < 64){
        float a = 0.f;
        for (int j = 0; j < H_; j++) a += out_w1[t*H_ + j] * out_w2[j];
        v_s[t] = a;
    }
    if (t == 64){
        float a = 0.f;
        for (int j = 0; j < H_; j++) a += out_b1[j] * out_w2[j];
        c_s = a + out_b2[0];
    }
    __syncthreads();
    if (t < 128){
        for (int l = 0; l < NL; l++){
            float a = 0.f;
            for (int o = 0; o < D_; o++) a += fc_w2[(l*H_ + t)*D_ + o] * v_s[o];
            ws[OFF_U + l*128 + t] = a;
        }
    }
    if (t >= 128 && t < 132){
        int l = t - 128;
        float a = 0.f;
        for (int o = 0; o < D_; o++) a += fc_b2[l*D_ + o] * v_s[o];
        ws[OFF_DD + l] = a + c_s;
    }
    const float isn = 0.08838834764831845f;  // 1/sqrt(128)
    for (int e = t; e < 128*32; e += 256){
        int n = e >> 5, kp = e & 31, k = kp >> 1;
        float ang = 6.283185307179586f * (float)((k*n) & 127) / 128.0f;
        // forward: Re = +cos/sqrtN ; Im = -sin/sqrtN
        ws[OFF_BF + e] = (kp & 1) ? (-sinf(ang)*isn) : (cosf(ang)*isn);
        // inverse: x[n] = sum_k Pre*ci + Pim*si
        float val;
        if (kp & 1) val = (k == 0) ? 0.f : (-2.f*sinf(ang)*isn);
        else        val = ((k == 0) ? 1.f : 2.f) * cosf(ang) * isn;
        ws[OFF_BI + e] = val;
    }
}

// ============ convert FF weights -> bf16, transposed ============
// layout in wb: [0..32767] bc_w1T [l][j128][i64]; [32768..] fc_w1T; [65536..] bc_w2T [l][o64][j128]
__global__ void k_wconv(const float* __restrict__ bc_w1, const float* __restrict__ fc_w1,
                        const float* __restrict__ bc_w2, float* __restrict__ ws){
    unsigned short* wb = (unsigned short*)(ws + OFF_WB);
    int e = blockIdx.x*256 + threadIdx.x;      // < 98304
    int a = e >> 15;
    int r = e & 32767;
    int l = r >> 13;
    int q = r & 8191;
    if (a == 0){
        int j = q >> 6, i = q & 63;
        wb[e] = f2bf(bc_w1[(l*D_ + i)*H_ + j]);
    } else if (a == 1){
        int j = q >> 6, i = q & 63;
        wb[e] = f2bf(fc_w1[(l*D_ + i)*H_ + j]);
    } else {
        int o = q >> 7, j = q & 127;
        wb[e] = f2bf(bc_w2[(l*H_ + j)*D_ + o]);
    }
}

// ============ input embedding ============
__global__ __launch_bounds__(256) void k_embed(const float* __restrict__ xin,
                                               const float* __restrict__ in_w,
                                               const float* __restrict__ in_b,
                                               float* __restrict__ X){
    long row = (long)blockIdx.x*4 + (threadIdx.x >> 6);
    int d = threadIdx.x & 63;
    const float* xr = xin + row*DIN;
    float acc = in_b[d];
    #pragma unroll
    for (int i = 0; i < DIN; i++) acc += xr[i] * in_w[i*D_ + d];
    X[row*D_ + d] = acc;
}

// ============ forward partial DFT (16 modes) ============
// axis==0: along n (contiguous). axis==1: along m (strided). rowid = bm or bn.
__global__ __launch_bounds__(256) void k_fwd(const float* __restrict__ X, const float* __restrict__ ws,
                                             float* __restrict__ Tre, float* __restrict__ Tim, int axis){
    __shared__ float Xs[128*64];
    __shared__ float Bft[128*32];
    int t = threadIdx.x;
    int rowid = blockIdx.x;
    long base; long strideN;
    if (axis == 0){ base = (long)rowid*8192; strideN = 64; }
    else { long b = rowid >> 7, nc = rowid & 127; base = b*1048576 + nc*64; strideN = 8192; }
    for (int e = t; e < 1024; e += 256)
        *(f32x4*)&Bft[e*4] = *(const f32x4*)&ws[OFF_BF + e*4];
    for (int c = t; c < 2048; c += 256){
        int n = c >> 4, c4 = c & 15;
        *(f32x4*)&Xs[n*64 + c4*4] = *(const f32x4*)&X[base + (long)n*strideN + c4*4];
    }
    __syncthreads();
    int i0 = (t & 31)*2;
    int kb = (t >> 5)*4;
    float acc[2][4];
    #pragma unroll
    for (int ii = 0; ii < 2; ii++) for (int kk = 0; kk < 4; kk++) acc[ii][kk] = 0.f;
    for (int n = 0; n < 128; n++){
        f32x2 xv = *(const f32x2*)&Xs[n*64 + i0];
        f32x4 bv = *(const f32x4*)&Bft[n*32 + kb];
        #pragma unroll
        for (int kk = 0; kk < 4; kk++){
            acc[0][kk] += xv[0]*bv[kk];
            acc[1][kk] += xv[1]*bv[kk];
        }
    }
    #pragma unroll
    for (int kk = 0; kk < 4; kk++){
        int kp = kb + kk, k = kp >> 1;
        float* dst = (kp & 1) ? Tim : Tre;
        dst[((long)k*NROW + rowid)*64 + i0    ] = acc[0][kk];
        dst[((long)k*NROW + rowid)*64 + i0 + 1] = acc[1][kk];
    }
}

// ============ per-mode complex channel mix ============
__global__ __launch_bounds__(256) void k_mix(const float* __restrict__ Tre, const float* __restrict__ Tim,
                                             const float* __restrict__ Wre_all, const float* __restrict__ Wim_all,
                                             float* __restrict__ Pre, float* __restrict__ Pim){
    __shared__ float Wre[4096], Wim[4096], Tr[4096], Ti[4096];
    int t = threadIdx.x;
    int k = blockIdx.y;
    long row0 = (long)blockIdx.x*64;
    for (int e = t; e < 4096; e += 256){
        Wre[e] = Wre_all[e*16 + k];
        Wim[e] = Wim_all[e*16 + k];
    }
    const float* sr = Tre + ((long)k*NROW + row0)*64;
    const float* si = Tim + ((long)k*NROW + row0)*64;
    for (int e = t; e < 1024; e += 256){
        *(f32x4*)&Tr[e*4] = *(const f32x4*)&sr[e*4];
        *(f32x4*)&Ti[e*4] = *(const f32x4*)&si[e*4];
    }
    __syncthreads();
    int r0 = (t >> 4)*4, o0 = (t & 15)*4;
    float ar[4][4] = {{0.f}}, ai[4][4] = {{0.f}};
    for (int i = 0; i < 64; i += 4){
        f32x4 tr[4], ti4[4];
        #pragma unroll
        for (int rr = 0; rr < 4; rr++){
            tr[rr]  = *(const f32x4*)&Tr[(r0+rr)*64 + i];
            ti4[rr] = *(const f32x4*)&Ti[(r0+rr)*64 + i];
        }
        #pragma unroll
        for (int ii = 0; ii < 4; ii++){
            f32x4 wr = *(const f32x4*)&Wre[(i+ii)*64 + o0];
            f32x4 wi = *(const f32x4*)&Wim[(i+ii)*64 + o0];
            #pragma unroll
            for (int rr = 0; rr < 4; rr++){
                float a = tr[rr][ii], b = ti4[rr][ii];
                #pragma unroll
                for (int cc = 0; cc < 4; cc++){
                    ar[rr][cc] += a*wr[cc] - b*wi[cc];
                    ai[rr][cc] += a*wi[cc] + b*wr[cc];
                }
            }
        }
    }
    float* dr = Pre + ((long)k*NROW + row0)*64;
    float* di = Pim + ((long)k*NROW + row0)*64;
    #pragma unroll
    for (int rr = 0; rr < 4; rr++){
        f32x4 vr, vi2;
        #pragma unroll
        for (int cc = 0; cc < 4; cc++){ vr[cc] = ar[rr][cc]; vi2[cc] = ai[rr][cc]; }
        *(f32x4*)&dr[(r0+rr)*64 + o0] = vr;
        *(f32x4*)&di[(r0+rr)*64 + o0] = vi2;
    }
}

// ============ inverse partial DFT ============
__global__ __launch_bounds__(256) void k_inv(const float* __restrict__ Pre, const float* __restrict__ Pim,
                                             const float* __restrict__ ws, float* __restrict__ XS,
                                             int axis, int accum){
    __shared__ float Ps[1024], Qs[1024], Bi[4096];
    int t = threadIdx.x;
    int rowid = blockIdx.x;
    for (int e = t; e < 1024; e += 256)
        *(f32x4*)&Bi[e*4] = *(const f32x4*)&ws[OFF_BI + e*4];
    for (int e = t; e < 1024; e += 256){
        int k = e >> 6, i = e & 63;
        Ps[e] = Pre[((long)k*NROW + rowid)*64 + i];
        Qs[e] = Pim[((long)k*NROW + rowid)*64 + i];
    }
    __syncthreads();
    int o0 = (t & 15)*4, n0 = (t >> 4)*8;
    float acc[8][4];
    #pragma unroll
    for (int nn = 0; nn < 8; nn++) for (int oo = 0; oo < 4; oo++) acc[nn][oo] = 0.f;
    for (int k = 0; k < 16; k++){
        f32x4 pr = *(const f32x4*)&Ps[k*64 + o0];
        f32x4 pi = *(const f32x4*)&Qs[k*64 + o0];
        #pragma unroll
        for (int nn = 0; nn < 8; nn++){
            f32x2 cs = *(const f32x2*)&Bi[(n0+nn)*32 + 2*k];
            #pragma unroll
            for (int oo = 0; oo < 4; oo++) acc[nn][oo] += pr[oo]*cs[0] + pi[oo]*cs[1];
        }
    }
    long base, strideN;
    if (axis == 0){ base = (long)rowid*8192; strideN = 64; }
    else { long b = rowid >> 7, nc = rowid & 127; base = b*1048576 + nc*64; strideN = 8192; }
    #pragma unroll
    for (int nn = 0; nn < 8; nn++){
        float* p = XS + base + (long)(n0+nn)*strideN + o0;
        f32x4 v;
        #pragma unroll
        for (int oo = 0; oo < 4; oo++) v[oo] = acc[nn][oo];
        if (accum){ f32x4 old = *(const f32x4*)p; v = v + old; }
        *(f32x4*)p = v;
    }
}

// ============ fused FeedForward block (bf16 MFMA) ============
// per 64-row tile: h1=relu(xs@bcw1+b1); x -= h1@bcw2+b2; h2=relu(xs@fcw1+fb1); out += h2.u + d
#define LDS_XS 0
#define LDS_W  8192
#define LDS_H  24576
__global__ __launch_bounds__(256) void k_ff(const float* __restrict__ XS, float* __restrict__ X,
                                            float* __restrict__ out, const float* __restrict__ ws,
                                            const float* __restrict__ bc_b1, const float* __restrict__ bc_b2,
                                            const float* __restrict__ fc_b1, int layer, int first){
    __shared__ __attribute__((aligned(16))) char lds[40960];
    int t = threadIdx.x;
    int w = t >> 6, lane = t & 63;
    long row0 = (long)blockIdx.x*64;
    const unsigned short* wb = (const unsigned short*)(ws + OFF_WB);

    // stage xs tile -> bf16, XOR-swizzled [64][64]
    for (int c = t; c < 512; c += 256){
        int r = c >> 3, c8 = c & 7;
        const float* src = XS + (row0 + r)*64 + c8*8;
        f32x4 v0 = *(const f32x4*)src;
        f32x4 v1 = *(const f32x4*)(src + 4);
        s16x8 s;
        s[0]=(short)f2bf(v0[0]); s[1]=(short)f2bf(v0[1]); s[2]=(short)f2bf(v0[2]); s[3]=(short)f2bf(v0[3]);
        s[4]=(short)f2bf(v1[0]); s[5]=(short)f2bf(v1[1]); s[6]=(short)f2bf(v1[2]); s[7]=(short)f2bf(v1[3]);
        *(s16x8*)(lds + LDS_XS + r*128 + ((c8 << 4) ^ ((r & 7) << 4))) = s;
    }
    // stage bc_w1T [128][64]
    {
        const u32x4* src = (const u32x4*)(wb + (long)layer*8192);
        for (int c = t; c < 1024; c += 256){
            int r = c >> 3, c8 = c & 7;
            *(u32x4*)(lds + LDS_W + r*128 + ((c8 << 4) ^ ((r & 7) << 4))) = src[c];
        }
    }
    __syncthreads();

    // ---- GEMM1 (bc): h = relu(xs @ w1 + b1) ----
    {
        f32x4 acc[8];
        #pragma unroll
        for (int nf = 0; nf < 8; nf++) acc[nf] = (f32x4){0.f,0.f,0.f,0.f};
        #pragma unroll
        for (int ks = 0; ks < 2; ks++){
            int arow = w*16 + (lane & 15);
            int kch = (lane >> 4) + ks*4;
            s16x8 a = *(const s16x8*)(lds + LDS_XS + arow*128 + ((kch << 4) ^ ((arow & 7) << 4)));
            #pragma unroll
            for (int nf = 0; nf < 8; nf++){
                int n = nf*16 + (lane & 15);
                s16x8 b = *(const s16x8*)(lds + LDS_W + n*128 + ((kch << 4) ^ ((n & 7) << 4)));
                acc[nf] = __builtin_amdgcn_mfma_f32_16x16x32_bf16(a, b, acc[nf], 0, 0, 0);
            }
        }
        #pragma unroll
        for (int nf = 0; nf < 8; nf++){
            int ncol = nf*16 + (lane & 15);
            float b1 = bc_b1[layer*128 + ncol];
            #pragma unroll
            for (int q = 0; q < 4; q++){
                int mrow = w*16 + (lane >> 4)*4 + q;
                float hv = fmaxf(acc[nf][q] + b1, 0.f);
                *(unsigned short*)(lds + LDS_H + mrow*256 + (((ncol >> 3) << 4) ^ ((mrow & 7) << 4)) + (ncol & 7)*2) = f2bf(hv);
            }
        }
    }
    __syncthreads();
    // stage bc_w2T [64][128]
    {
        const u32x4* src = (const u32x4*)(wb + 65536 + (long)layer*8192);
        for (int c = t; c < 1024; c += 256){
            int r = c >> 4, c16 = c & 15;
            *(u32x4*)(lds + LDS_W + r*256 + ((c16 << 4) ^ ((r & 7) << 4))) = src[c];
        }
    }
    __syncthreads();
    // ---- GEMM2: x_next = x - (h @ w2 + b2) ----
    {
        f32x4 acc[4];
        #pragma unroll
        for (int nf = 0; nf < 4; nf++) acc[nf] = (f32x4){0.f,0.f,0.f,0.f};
        #pragma unroll
        for (int ks = 0; ks < 4; ks++){
            int arow = w*16 + (lane & 15);
            int kch = (lane >> 4) + ks*4;
            s16x8 a = *(const s16x8*)(lds + LDS_H + arow*256 + ((kch << 4) ^ ((arow & 7) << 4)));
            #pragma unroll
            for (int nf = 0; nf < 4; nf++){
                int n = nf*16 + (lane & 15);
                s16x8 b = *(const s16x8*)(lds + LDS_W + n*256 + ((kch << 4) ^ ((n & 7) << 4)));
                acc[nf] = __builtin_amdgcn_mfma_f32_16x16x32_bf16(a, b, acc[nf], 0, 0, 0);
            }
        }
        #pragma unroll
        for (int nf = 0; nf < 4; nf++){
            int ncol = nf*16 + (lane & 15);
            float b2 = bc_b2[layer*64 + ncol];
            #pragma unroll
            for (int q = 0; q < 4; q++){
                int mrow = w*16 + (lane >> 4)*4 + q;
                long g = (row0 + mrow)*64 + ncol;
                X[g] = X[g] - (acc[nf][q] + b2);
            }
        }
    }
    __syncthreads();
    // stage fc_w1T [128][64]
    {
        const u32x4* src = (const u32x4*)(wb + 32768 + (long)layer*8192);
        for (int c = t; c < 1024; c += 256){
            int r = c >> 3, c8 = c & 7;
            *(u32x4*)(lds + LDS_W + r*128 + ((c8 << 4) ^ ((r & 7) << 4))) = src[c];
        }
    }
    __syncthreads();
    // ---- GEMM1 (fc): h2 = relu(xs @ fw1 + fb1) ----
    {
        f32x4 acc[8];
        #pragma unroll
        for (int nf = 0; nf < 8; nf++) acc[nf] = (f32x4){0.f,0.f,0.f,0.f};
        #pragma unroll
        for (int ks = 0; ks < 2; ks++){
            int arow = w*16 + (lane & 15);
            int kch = (lane >> 4) + ks*4;
            s16x8 a = *(const s16x8*)(lds + LDS_XS + arow*128 + ((kch << 4) ^ ((arow & 7) << 4)));
            #pragma unroll
            for (int nf = 0; nf < 8; nf++){
                int n = nf*16 + (lane & 15);
                s16x8 b = *(const s16x8*)(lds + LDS_W + n*128 + ((kch << 4) ^ ((n & 7) << 4)));
                acc[nf] = __builtin_amdgcn_mfma_f32_16x16x32_bf16(a, b, acc[nf], 0, 0, 0);
            }
        }
        #pragma unroll
        for (int nf = 0; nf < 8; nf++){
            int ncol = nf*16 + (lane & 15);
            float b1 = fc_b1[layer*128 + ncol];
            #pragma unroll
            for (int q = 0; q < 4; q++){
                int mrow = w*16 + (lane >> 4)*4 + q;
                float hv = fmaxf(acc[nf][q] + b1, 0.f);
                *(unsigned short*)(lds + LDS_H + mrow*256 + (((ncol >> 3) << 4) ^ ((mrow & 7) << 4)) + (ncol & 7)*2) = f2bf(hv);
            }
        }
    }
    __syncthreads();
    // ---- f_out = h2 . u + d ; forecast accumulate ----
    if (t < 128){
        int r = t >> 1, half = t & 1;
        const float* up = ws + OFF_U + layer*128 + half*64;
        float sum = 0.f;
        #pragma unroll
        for (int c = 0; c < 8; c++){
            int kch = half*8 + c;
            s16x8 hv = *(const s16x8*)(lds + LDS_H + r*256 + ((kch << 4) ^ ((r & 7) << 4)));
            #pragma unroll
            for (int e = 0; e < 8; e++) sum += bf2f((unsigned short)hv[e]) * up[c*8 + e];
        }
        sum += __shfl_xor(sum, 1);
        if (half == 0){
            float fo = sum + ws[OFF_DD + layer];
            long g = row0 + r;
            if (first) out[g] = fo; else out[g] += fo;
        }
    }
}

// ============ host launch ============
extern "C" void kernel_launch(void* const* d_in, const int* in_sizes, int n_in,
                              void* d_out, int out_size, void* d_ws, size_t ws_size,
                              hipStream_t stream){
    if (ws_size < (size_t)WS_NEEDED_BYTES) return;  // fail loudly via wrong output
    const float* xin    = (const float*)d_in[0];
    const float* in_w   = (const float*)d_in[1];
    const float* in_b   = (const float*)d_in[2];
    const float* fwy_re = (const float*)d_in[3];
    const float* fwy_im = (const float*)d_in[4];
    const float* fwx_re = (const float*)d_in[5];
    const float* fwx_im = (const float*)d_in[6];
    const float* bc_w1  = (const float*)d_in[7];
    const float* bc_b1  = (const float*)d_in[8];
    const float* bc_w2  = (const float*)d_in[9];
    const float* bc_b2  = (const float*)d_in[10];
    const float* fc_w1  = (const float*)d_in[11];
    const float* fc_b1  = (const float*)d_in[12];
    const float* fc_w2  = (const float*)d_in[13];
    const float* fc_b2  = (const float*)d_in[14];
    const float* out_w1 = (const float*)d_in[15];
    const float* out_b1 = (const float*)d_in[16];
    const float* out_w2 = (const float*)d_in[17];
    const float* out_b2 = (const float*)d_in[18];
    float* ws  = (float*)d_ws;
    float* out = (float*)d_out;

    k_init<<<1, 256, 0, stream>>>(out_w1, out_b1, out_w2, out_b2, fc_w2, fc_b2, ws);
    k_wconv<<<384, 256, 0, stream>>>(bc_w1, fc_w1, bc_w2, ws);
    k_embed<<<NPIX/4, 256, 0, stream>>>(xin, in_w, in_b, ws + OFF_X);

    for (int l = 0; l < NL; l++){
        // x-axis (along m): init XS
        k_fwd<<<NROW, 256, 0, stream>>>(ws + OFF_X, ws, ws + OFF_TRE, ws + OFF_TIM, 1);
        k_mix<<<dim3(32, 16), 256, 0, stream>>>(ws + OFF_TRE, ws + OFF_TIM,
                                                fwx_re + (long)l*65536, fwx_im + (long)l*65536,
                                                ws + OFF_PRE, ws + OFF_PIM);
        k_inv<<<NROW, 256, 0, stream>>>(ws + OFF_PRE, ws + OFF_PIM, ws, ws + OFF_XS, 1, 0);
        // y-axis (along n): accumulate into XS
        k_fwd<<<NROW, 256, 0, stream>>>(ws + OFF_X, ws, ws + OFF_TRE, ws + OFF_TIM, 0);
        k_mix<<<dim3(32, 16), 256, 0, stream>>>(ws + OFF_TRE, ws + OFF_TIM,
                                                fwy_re + (long)l*65536, fwy_im + (long)l*65536,
                                                ws + OFF_PRE, ws + OFF_PIM);
        k_inv<<<NROW, 256, 0, stream>>>(ws + OFF_PRE, ws + OFF_PIM, ws, ws + OFF_XS, 0, 1);
        // fused FF: updates X (next input), accumulates forecast
        k_ff<<<NPIX/64, 256, 0, stream>>>(ws + OFF_XS, ws + OFF_X, out, ws,
                                          bc_b1, bc_b2, fc_b1, l, l == 0 ? 1 : 0);
    }
}

// Round 2
// 620.221 us; speedup vs baseline: 1.8739x; 1.8739x over previous
//
#include <hip/hip_runtime.h>

// ---------------- problem constants ----------------
#define B_    16
#define M_    128
#define N_    128
#define DIN   12
#define D_    64
#define H_    128
#define MODES 16
#define NL    4
#define NPIX  262144       // B*M*N

// ---------------- vector types ----------------
typedef float  f32x2 __attribute__((ext_vector_type(2)));
typedef float  f32x4 __attribute__((ext_vector_type(4)));
typedef short  s16x8 __attribute__((ext_vector_type(8)));
typedef unsigned int u32x4 __attribute__((ext_vector_type(4)));

// ---------------- workspace layout (BYTE offsets) ----------------
#define WSB_X      0L            // [B,M,N,64] f32                67108864
#define WSB_XSX    67108864L     // [B,M,N,64] bf16 (x-axis part) 33554432
#define WSB_BF     100663296L    // fwd basis bf16 [kp=32][n=128]  8192
#define WSB_BI     100671488L    // inv basis bf16 [n=128][kp=32]  8192
#define WSB_U      100679680L    // u[4][128] f32                  2048
#define WSB_D      100681728L    // d[4] f32                       16
#define WSB_WFF    100681744L    // FF weights bf16 (3x4x8192 u16) 196608
#define WSB_WMIX   100878352L    // mix weights u32(re|im) [ax][l][k][i][o] 2097152
#define WS_NEEDED  102975504L

__device__ __forceinline__ unsigned short f2bf(float f){
    unsigned int u = __float_as_uint(f);
    u += 0x7fffu + ((u >> 16) & 1u);
    return (unsigned short)(u >> 16);
}
__device__ __forceinline__ float bf2f(unsigned short s){
    return __uint_as_float(((unsigned int)s) << 16);
}

// ============ init: bf16 basis tables + collapsed output head ============
__global__ void k_init(const float* __restrict__ out_w1, const float* __restrict__ out_b1,
                       const float* __restrict__ out_w2, const float* __restrict__ out_b2,
                       const float* __restrict__ fc_w2, const float* __restrict__ fc_b2,
                       float* __restrict__ ws){
    __shared__ float v_s[64];
    __shared__ float c_s;
    int t = threadIdx.x;
    if (t < 64){
        float a = 0.f;
        for (int j = 0; j < H_; j++) a += out_w1[t*H_ + j] * out_w2[j];
        v_s[t] = a;
    }
    if (t == 64){
        float a = 0.f;
        for (int j = 0; j < H_; j++) a += out_b1[j] * out_w2[j];
        c_s = a + out_b2[0];
    }
    __syncthreads();
    float* uw = (float*)((char*)ws + WSB_U);
    float* dw = (float*)((char*)ws + WSB_D);
    if (t < 128){
        for (int l = 0; l < NL; l++){
            float a = 0.f;
            for (int o = 0; o < D_; o++) a += fc_w2[(l*H_ + t)*D_ + o] * v_s[o];
            uw[l*128 + t] = a;
        }
    }
    if (t >= 128 && t < 132){
        int l = t - 128;
        float a = 0.f;
        for (int o = 0; o < D_; o++) a += fc_b2[l*D_ + o] * v_s[o];
        dw[l] = a + c_s;
    }
    const float isn = 0.08838834764831845f;  // 1/sqrt(128)
    unsigned short* bft = (unsigned short*)((char*)ws + WSB_BF);
    unsigned short* bit = (unsigned short*)((char*)ws + WSB_BI);
    for (int e = t; e < 4096; e += 256){
        // fwd basis [kp][n]
        { int kp = e >> 7, n = e & 127, k = kp >> 1;
          float ang = 6.283185307179586f * (float)((k*n) & 127) / 128.0f;
          bft[e] = f2bf((kp & 1) ? (-sinf(ang)*isn) : (cosf(ang)*isn)); }
        // inv basis [n][kp]
        { int n = e >> 5, kp = e & 31, k = kp >> 1;
          float ang = 6.283185307179586f * (float)((k*n) & 127) / 128.0f;
          float val;
          if (kp & 1) val = (k == 0) ? 0.f : (-2.f*sinf(ang)*isn);
          else        val = ((k == 0) ? 1.f : 2.f) * cosf(ang) * isn;
          bit[e] = f2bf(val); }
    }
}

// ============ FF weights -> bf16 transposed ============
// wb u16: [0..32767] bc_w1T [l][j128][i64]; [32768..] fc_w1T; [65536..] bc_w2T [l][o64][j128]
__global__ void k_wconv(const float* __restrict__ bc_w1, const float* __restrict__ fc_w1,
                        const float* __restrict__ bc_w2, float* __restrict__ ws){
    unsigned short* wb = (unsigned short*)((char*)ws + WSB_WFF);
    int e = blockIdx.x*256 + threadIdx.x;      // < 98304
    int a = e >> 15;
    int r = e & 32767;
    int l = r >> 13;
    int q = r & 8191;
    if (a == 0){
        int j = q >> 6, i = q & 63;
        wb[e] = f2bf(bc_w1[(l*D_ + i)*H_ + j]);
    } else if (a == 1){
        int j = q >> 6, i = q & 63;
        wb[e] = f2bf(fc_w1[(l*D_ + i)*H_ + j]);
    } else {
        int o = q >> 7, j = q & 127;
        wb[e] = f2bf(bc_w2[(l*H_ + j)*D_ + o]);
    }
}

// ============ mix weights -> packed bf16 u32 [ax][l][k][i][o] ============
__global__ void k_wmix(const float* __restrict__ fwy_re, const float* __restrict__ fwy_im,
                       const float* __restrict__ fwx_re, const float* __restrict__ fwx_im,
                       float* __restrict__ ws){
    unsigned int* wm = (unsigned int*)((char*)ws + WSB_WMIX);
    int e = blockIdx.x*256 + threadIdx.x;   // < 524288
    int ax = e >> 18;
    int r  = e & 262143;
    int l  = r >> 16;
    int k  = (r >> 12) & 15;
    int i  = (r >> 6) & 63;
    int o  = r & 63;
    long sidx = (((long)l*64 + i)*64 + o)*16 + k;
    float re = ax ? fwx_re[sidx] : fwy_re[sidx];
    float im = ax ? fwx_im[sidx] : fwy_im[sidx];
    wm[e] = (unsigned int)f2bf(re) | ((unsigned int)f2bf(im) << 16);
}

// ============ input embedding ============
__global__ __launch_bounds__(256) void k_embed(const float* __restrict__ xin,
                                               const float* __restrict__ in_w,
                                               const float* __restrict__ in_b,
                                               float* __restrict__ X){
    long row = (long)blockIdx.x*4 + (threadIdx.x >> 6);
    int d = threadIdx.x & 63;
    const float* xr = xin + row*DIN;
    float acc = in_b[d];
    #pragma unroll
    for (int i = 0; i < DIN; i++) acc += xr[i] * in_w[i*D_ + d];
    X[row*D_ + d] = acc;
}

// ============ K1: fused x-axis spectral conv (fwd+mix+inv), 2 col-slabs/block ====
// block = (b, nc-pair). DFT along m. Writes XSx bf16 [b][m][nc][o].
__global__ __launch_bounds__(256, 3) void k_spec_x(float* __restrict__ ws_f, int layer){
    __shared__ __attribute__((aligned(16))) char lds[49152];
    // regions: XsT s*16384 (0..32767) | Bf 32768..40959 | T 40960+s*4096
    // after fwd: Bi 0..10239 | P 10240+s*5120
    int t = threadIdx.x, w = t >> 6, lane = t & 63;
    int l15 = lane & 15, l4 = lane >> 4;
    int bb = blockIdx.x >> 6;
    int c  = blockIdx.x & 63;
    const float* X = ws_f;

    // ---- stage XsT (transposed [i][m]) for both slabs + Bf ----
    for (int s = 0; s < 2; s++){
        long base = (long)bb*1048576 + (long)(c*2 + s)*64;
        char* xst = lds + s*16384;
        #pragma unroll
        for (int it = 0; it < 4; it++){
            int iq = t & 15, np = (t >> 4) + it*16;
            int i0 = iq*4;
            f32x4 v0 = *(const f32x4*)&X[base + (long)(2*np)*8192 + i0];
            f32x4 v1 = *(const f32x4*)&X[base + (long)(2*np + 1)*8192 + i0];
            #pragma unroll
            for (int j = 0; j < 4; j++){
                int i = i0 + j;
                unsigned int pk = (unsigned int)f2bf(v0[j]) | ((unsigned int)f2bf(v1[j]) << 16);
                *(unsigned int*)(xst + i*256 + ((np*4) ^ ((i & 15) << 4))) = pk;
            }
        }
    }
    {
        const unsigned short* bfg = (const unsigned short*)((char*)ws_f + WSB_BF);
        for (int e = t; e < 512; e += 256){
            int kp = e >> 4, c16 = e & 15;
            s16x8 v = *(const s16x8*)&bfg[e*8];
            *(s16x8*)(lds + 32768 + kp*256 + ((c16*16) ^ ((kp & 7) << 4))) = v;
        }
    }
    __syncthreads();

    // ---- fwd MFMA: T[kp=32][i=64] = Bf @ X ----
    int mt = w & 1, nt0 = (w >> 1)*2;
    for (int s = 0; s < 2; s++){
        char* xst = lds + s*16384;
        f32x4 acc[2] = {{0.f,0.f,0.f,0.f},{0.f,0.f,0.f,0.f}};
        #pragma unroll
        for (int ks = 0; ks < 4; ks++){
            int kpr = mt*16 + l15;
            s16x8 a = *(const s16x8*)(lds + 32768 + kpr*256 + (((l4*16) + ks*64) ^ ((kpr & 7) << 4)));
            #pragma unroll
            for (int nf = 0; nf < 2; nf++){
                int i = (nt0 + nf)*16 + l15;
                s16x8 b = *(const s16x8*)(xst + i*256 + (((l4*16) + ks*64) ^ ((i & 15) << 4)));
                acc[nf] = __builtin_amdgcn_mfma_f32_16x16x32_bf16(a, b, acc[nf], 0, 0, 0);
            }
        }
        char* Ts = lds + 40960 + s*4096;
        #pragma unroll
        for (int nf = 0; nf < 2; nf++){
            int i = (nt0 + nf)*16 + l15;
            #pragma unroll
            for (int q = 0; q < 4; q++){
                int kp = mt*16 + l4*4 + q;
                *(unsigned short*)(Ts + kp*128 + ((i*2) ^ ((kp & 7) << 4))) = f2bf(acc[nf][q]);
            }
        }
    }
    __syncthreads();

    // ---- Bi stage (XsT dead) + mix (vector fp32, both slabs share W loads) ----
    {
        const unsigned short* big = (const unsigned short*)((char*)ws_f + WSB_BI);
        for (int e = t; e < 512; e += 256){
            int n = e >> 2, k8 = e & 3;
            s16x8 v = *(const s16x8*)&big[e*8];
            *(s16x8*)(lds + n*80 + ((k8*16) ^ ((n & 3) << 4))) = v;
        }
    }
    {
        int k = t >> 4, og = t & 15;
        const unsigned int* Wg = (const unsigned int*)((char*)ws_f + WSB_WMIX)
                                 + ((long)(4 + layer)*16 + k)*4096;   // axis=1 (fwx)
        const char* T0 = lds + 40960;
        const char* T1 = lds + 45056;
        int rre = 2*k, rim = 2*k + 1;
        float pre0[4] = {0,0,0,0}, pim0[4] = {0,0,0,0};
        float pre1[4] = {0,0,0,0}, pim1[4] = {0,0,0,0};
        for (int i0 = 0; i0 < 64; i0 += 8){
            s16x8 tr0 = *(const s16x8*)(T0 + rre*128 + ((i0*2) ^ ((rre & 7) << 4)));
            s16x8 ti0 = *(const s16x8*)(T0 + rim*128 + ((i0*2) ^ ((rim & 7) << 4)));
            s16x8 tr1 = *(const s16x8*)(T1 + rre*128 + ((i0*2) ^ ((rre & 7) << 4)));
            s16x8 ti1 = *(const s16x8*)(T1 + rim*128 + ((i0*2) ^ ((rim & 7) << 4)));
            #pragma unroll
            for (int e = 0; e < 8; e++){
                u32x4 wv = *(const u32x4*)&Wg[(i0 + e)*64 + og*4];
                float a0 = bf2f((unsigned short)tr0[e]), b0 = bf2f((unsigned short)ti0[e]);
                float a1 = bf2f((unsigned short)tr1[e]), b1 = bf2f((unsigned short)ti1[e]);
                #pragma unroll
                for (int j = 0; j < 4; j++){
                    float wre = bf2f((unsigned short)(wv[j] & 0xffffu));
                    float wim = bf2f((unsigned short)(wv[j] >> 16));
                    pre0[j] += a0*wre - b0*wim;  pim0[j] += a0*wim + b0*wre;
                    pre1[j] += a1*wre - b1*wim;  pim1[j] += a1*wim + b1*wre;
                }
            }
        }
        #pragma unroll
        for (int j = 0; j < 4; j++){
            int o = og*4 + j;
            unsigned int pk0 = (unsigned int)f2bf(pre0[j]) | ((unsigned int)f2bf(pim0[j]) << 16);
            unsigned int pk1 = (unsigned int)f2bf(pre1[j]) | ((unsigned int)f2bf(pim1[j]) << 16);
            *(unsigned int*)(lds + 10240 + o*80 + ((k*4) ^ ((o & 3) << 4))) = pk0;
            *(unsigned int*)(lds + 15360 + o*80 + ((k*4) ^ ((o & 3) << 4))) = pk1;
        }
    }
    __syncthreads();

    // ---- inv MFMA: XSx[m=128][o=64] = Bi @ P ; write bf16 global ----
    unsigned short* XSx = (unsigned short*)((char*)ws_f + WSB_XSX);
    for (int s = 0; s < 2; s++){
        const char* Ps = lds + 10240 + s*5120;
        int nc = c*2 + s;
        s16x8 bfr[4];
        #pragma unroll
        for (int nt = 0; nt < 4; nt++){
            int o = nt*16 + l15;
            bfr[nt] = *(const s16x8*)(Ps + o*80 + ((l4*16) ^ ((o & 3) << 4)));
        }
        f32x4 acc[2][4];
        #pragma unroll
        for (int mi = 0; mi < 2; mi++){
            int n_ = (w*2 + mi)*16 + l15;
            s16x8 a = *(const s16x8*)(lds + n_*80 + ((l4*16) ^ ((n_ & 3) << 4)));
            #pragma unroll
            for (int nt = 0; nt < 4; nt++){
                f32x4 z = {0.f,0.f,0.f,0.f};
                acc[mi][nt] = __builtin_amdgcn_mfma_f32_16x16x32_bf16(a, bfr[nt], z, 0, 0, 0);
            }
        }
        #pragma unroll
        for (int mi = 0; mi < 2; mi++)
        #pragma unroll
        for (int nt = 0; nt < 4; nt++)
        #pragma unroll
        for (int q = 0; q < 4; q++){
            int m = (w*2 + mi)*16 + l4*4 + q;
            int o = nt*16 + l15;
            XSx[(long)bb*1048576 + (long)m*8192 + nc*64 + o] = f2bf(acc[mi][nt][q]);
        }
    }
}

// ============ K2: fused y-axis spectral conv + FeedForward block ============
// block = (b, m) slab. DFT along n; XS = xy + XSx; then FF (bc update X, fc->forecast).
__global__ __launch_bounds__(256, 2) void k_spec_y_ff(
        float* __restrict__ ws_f, float* __restrict__ out,
        const float* __restrict__ bc_b1, const float* __restrict__ bc_b2,
        const float* __restrict__ fc_b1, int layer, int first){
    __shared__ __attribute__((aligned(16))) char lds[65536];
    // XsT 0..16383 (-> XS_lds after); Bf 16384..24575 (-> Wff); T 32768..36863;
    // Bi 36864..47103; P 47104..52223; H 32768..65535 (after spectral)
    int t = threadIdx.x, w = t >> 6, lane = t & 63;
    int l15 = lane & 15, l4 = lane >> 4;
    long slab = blockIdx.x;                 // b*128 + m
    float* X = ws_f;
    long xbase = slab*8192;

    // ---- stage XsT transposed [i][n] + Bf + Bi ----
    #pragma unroll
    for (int it = 0; it < 4; it++){
        int iq = t & 15, np = (t >> 4) + it*16;
        int i0 = iq*4;
        f32x4 v0 = *(const f32x4*)&X[xbase + (long)(2*np)*64 + i0];
        f32x4 v1 = *(const f32x4*)&X[xbase + (long)(2*np + 1)*64 + i0];
        #pragma unroll
        for (int j = 0; j < 4; j++){
            int i = i0 + j;
            unsigned int pk = (unsigned int)f2bf(v0[j]) | ((unsigned int)f2bf(v1[j]) << 16);
            *(unsigned int*)(lds + i*256 + ((np*4) ^ ((i & 15) << 4))) = pk;
        }
    }
    {
        const unsigned short* bfg = (const unsigned short*)((char*)ws_f + WSB_BF);
        for (int e = t; e < 512; e += 256){
            int kp = e >> 4, c16 = e & 15;
            s16x8 v = *(const s16x8*)&bfg[e*8];
            *(s16x8*)(lds + 16384 + kp*256 + ((c16*16) ^ ((kp & 7) << 4))) = v;
        }
        const unsigned short* big = (const unsigned short*)((char*)ws_f + WSB_BI);
        for (int e = t; e < 512; e += 256){
            int n = e >> 2, k8 = e & 3;
            s16x8 v = *(const s16x8*)&big[e*8];
            *(s16x8*)(lds + 36864 + n*80 + ((k8*16) ^ ((n & 3) << 4))) = v;
        }
    }
    __syncthreads();

    // ---- fwd MFMA ----
    {
        int mt = w & 1, nt0 = (w >> 1)*2;
        f32x4 acc[2] = {{0.f,0.f,0.f,0.f},{0.f,0.f,0.f,0.f}};
        #pragma unroll
        for (int ks = 0; ks < 4; ks++){
            int kpr = mt*16 + l15;
            s16x8 a = *(const s16x8*)(lds + 16384 + kpr*256 + (((l4*16) + ks*64) ^ ((kpr & 7) << 4)));
            #pragma unroll
            for (int nf = 0; nf < 2; nf++){
                int i = (nt0 + nf)*16 + l15;
                s16x8 b = *(const s16x8*)(lds + i*256 + (((l4*16) + ks*64) ^ ((i & 15) << 4)));
                acc[nf] = __builtin_amdgcn_mfma_f32_16x16x32_bf16(a, b, acc[nf], 0, 0, 0);
            }
        }
        #pragma unroll
        for (int nf = 0; nf < 2; nf++){
            int i = (nt0 + nf)*16 + l15;
            #pragma unroll
            for (int q = 0; q < 4; q++){
                int kp = mt*16 + l4*4 + q;
                *(unsigned short*)(lds + 32768 + kp*128 + ((i*2) ^ ((kp & 7) << 4))) = f2bf(acc[nf][q]);
            }
        }
    }
    __syncthreads();

    // ---- mix (axis=0, fwy) ----
    {
        int k = t >> 4, og = t & 15;
        const unsigned int* Wg = (const unsigned int*)((char*)ws_f + WSB_WMIX)
                                 + ((long)layer*16 + k)*4096;
        const char* T0 = lds + 32768;
        int rre = 2*k, rim = 2*k + 1;
        float pre[4] = {0,0,0,0}, pim[4] = {0,0,0,0};
        for (int i0 = 0; i0 < 64; i0 += 8){
            s16x8 tr = *(const s16x8*)(T0 + rre*128 + ((i0*2) ^ ((rre & 7) << 4)));
            s16x8 ti = *(const s16x8*)(T0 + rim*128 + ((i0*2) ^ ((rim & 7) << 4)));
            #pragma unroll
            for (int e = 0; e < 8; e++){
                u32x4 wv = *(const u32x4*)&Wg[(i0 + e)*64 + og*4];
                float a0 = bf2f((unsigned short)tr[e]), b0 = bf2f((unsigned short)ti[e]);
                #pragma unroll
                for (int j = 0; j < 4; j++){
                    float wre = bf2f((unsigned short)(wv[j] & 0xffffu));
                    float wim = bf2f((unsigned short)(wv[j] >> 16));
                    pre[j] += a0*wre - b0*wim;
                    pim[j] += a0*wim + b0*wre;
                }
            }
        }
        #pragma unroll
        for (int j = 0; j < 4; j++){
            int o = og*4 + j;
            unsigned int pk = (unsigned int)f2bf(pre[j]) | ((unsigned int)f2bf(pim[j]) << 16);
            *(unsigned int*)(lds + 47104 + o*80 + ((k*4) ^ ((o & 3) << 4))) = pk;
        }
    }
    __syncthreads();

    // ---- inv MFMA + XSx add -> XS_lds bf16 [n][o] ----
    {
        const unsigned short* XSxg = (const unsigned short*)((char*)ws_f + WSB_XSX) + slab*8192;
        s16x8 bfr[4];
        #pragma unroll
        for (int nt = 0; nt < 4; nt++){
            int o = nt*16 + l15;
            bfr[nt] = *(const s16x8*)(lds + 47104 + o*80 + ((l4*16) ^ ((o & 3) << 4)));
        }
        f32x4 acc[2][4];
        #pragma unroll
        for (int mi = 0; mi < 2; mi++){
            int n_ = (w*2 + mi)*16 + l15;
            s16x8 a = *(const s16x8*)(lds + 36864 + n_*80 + ((l4*16) ^ ((n_ & 3) << 4)));
            #pragma unroll
            for (int nt = 0; nt < 4; nt++){
                f32x4 z = {0.f,0.f,0.f,0.f};
                acc[mi][nt] = __builtin_amdgcn_mfma_f32_16x16x32_bf16(a, bfr[nt], z, 0, 0, 0);
            }
        }
        #pragma unroll
        for (int mi = 0; mi < 2; mi++)
        #pragma unroll
        for (int nt = 0; nt < 4; nt++)
        #pragma unroll
        for (int q = 0; q < 4; q++){
            int n_ = (w*2 + mi)*16 + l4*4 + q;
            int o = nt*16 + l15;
            float v = acc[mi][nt][q] + bf2f(XSxg[n_*64 + o]);
            *(unsigned short*)(lds + n_*128 + ((o*2) ^ ((n_ & 7) << 4))) = f2bf(v);
        }
    }
    // stage bc_w1T -> 16384 (Bf dead)
    const unsigned short* wb = (const unsigned short*)((char*)ws_f + WSB_WFF);
    {
        const u32x4* src = (const u32x4*)(wb + (long)layer*8192);
        for (int cq = t; cq < 1024; cq += 256){
            int r = cq >> 3, c8 = cq & 7;
            *(u32x4*)(lds + 16384 + r*128 + ((c8 << 4) ^ ((r & 7) << 4))) = src[cq];
        }
    }
    __syncthreads();

    // ---- FF GEMM1 (bc): h = relu(xs@w1+b1) -> H ----
    {
        f32x4 acc[2][8];
        #pragma unroll
        for (int mi = 0; mi < 2; mi++)
        #pragma unroll
        for (int nf = 0; nf < 8; nf++) acc[mi][nf] = (f32x4){0.f,0.f,0.f,0.f};
        #pragma unroll
        for (int ks = 0; ks < 2; ks++){
            int kch = l4 + ks*4;
            int r0 = w*32 + l15, r1 = w*32 + 16 + l15;
            s16x8 a0 = *(const s16x8*)(lds + r0*128 + ((kch << 4) ^ ((r0 & 7) << 4)));
            s16x8 a1 = *(const s16x8*)(lds + r1*128 + ((kch << 4) ^ ((r1 & 7) << 4)));
            #pragma unroll
            for (int nf = 0; nf < 8; nf++){
                int n = nf*16 + l15;
                s16x8 b = *(const s16x8*)(lds + 16384 + n*128 + ((kch << 4) ^ ((n & 7) << 4)));
                acc[0][nf] = __builtin_amdgcn_mfma_f32_16x16x32_bf16(a0, b, acc[0][nf], 0, 0, 0);
                acc[1][nf] = __builtin_amdgcn_mfma_f32_16x16x32_bf16(a1, b, acc[1][nf], 0, 0, 0);
            }
        }
        #pragma unroll
        for (int mi = 0; mi < 2; mi++)
        #pragma unroll
        for (int nf = 0; nf < 8; nf++){
            int ncol = nf*16 + l15;
            float b1 = bc_b1[layer*128 + ncol];
            #pragma unroll
            for (int q = 0; q < 4; q++){
                int mrow = w*32 + mi*16 + l4*4 + q;
                float hv = fmaxf(acc[mi][nf][q] + b1, 0.f);
                *(unsigned short*)(lds + 32768 + mrow*256 + (((ncol >> 3) << 4) ^ ((mrow & 7) << 4)) + (ncol & 7)*2) = f2bf(hv);
            }
        }
    }
    __syncthreads();
    // stage bc_w2T [64][128] -> 16384
    {
        const u32x4* src = (const u32x4*)(wb + 65536 + (long)layer*8192);
        for (int cq = t; cq < 1024; cq += 256){
            int r = cq >> 4, c16 = cq & 15;
            *(u32x4*)(lds + 16384 + r*256 + ((c16 << 4) ^ ((r & 7) << 4))) = src[cq];
        }
    }
    __syncthreads();
    // ---- GEMM2: X = X - (h@w2+b2) ----
    {
        f32x4 acc[2][4];
        #pragma unroll
        for (int mi = 0; mi < 2; mi++)
        #pragma unroll
        for (int nf = 0; nf < 4; nf++) acc[mi][nf] = (f32x4){0.f,0.f,0.f,0.f};
        #pragma unroll
        for (int ks = 0; ks < 4; ks++){
            int kch = l4 + ks*4;
            int r0 = w*32 + l15, r1 = w*32 + 16 + l15;
            s16x8 a0 = *(const s16x8*)(lds + 32768 + r0*256 + ((kch << 4) ^ ((r0 & 7) << 4)));
            s16x8 a1 = *(const s16x8*)(lds + 32768 + r1*256 + ((kch << 4) ^ ((r1 & 7) << 4)));
            #pragma unroll
            for (int nf = 0; nf < 4; nf++){
                int n = nf*16 + l15;
                s16x8 b = *(const s16x8*)(lds + 16384 + n*256 + ((kch << 4) ^ ((n & 7) << 4)));
                acc[0][nf] = __builtin_amdgcn_mfma_f32_16x16x32_bf16(a0, b, acc[0][nf], 0, 0, 0);
                acc[1][nf] = __builtin_amdgcn_mfma_f32_16x16x32_bf16(a1, b, acc[1][nf], 0, 0, 0);
            }
        }
        #pragma unroll
        for (int mi = 0; mi < 2; mi++)
        #pragma unroll
        for (int nf = 0; nf < 4; nf++){
            int ncol = nf*16 + l15;
            float b2 = bc_b2[layer*64 + ncol];
            #pragma unroll
            for (int q = 0; q < 4; q++){
                int mrow = w*32 + mi*16 + l4*4 + q;
                long g = xbase + (long)mrow*64 + ncol;
                X[g] = X[g] - (acc[mi][nf][q] + b2);
            }
        }
    }
    __syncthreads();
    // stage fc_w1T -> 16384
    {
        const u32x4* src = (const u32x4*)(wb + 32768 + (long)layer*8192);
        for (int cq = t; cq < 1024; cq += 256){
            int r = cq >> 3, c8 = cq & 7;
            *(u32x4*)(lds + 16384 + r*128 + ((c8 << 4) ^ ((r & 7) << 4))) = src[cq];
        }
    }
    __syncthreads();
    // ---- GEMM3 (fc): h2 = relu(xs@fw1+fb1) -> H ----
    {
        f32x4 acc[2][8];
        #pragma unroll
        for (int mi = 0; mi < 2; mi++)
        #pragma unroll
        for (int nf = 0; nf < 8; nf++) acc[mi][nf] = (f32x4){0.f,0.f,0.f,0.f};
        #pragma unroll
        for (int ks = 0; ks < 2; ks++){
            int kch = l4 + ks*4;
            int r0 = w*32 + l15, r1 = w*32 + 16 + l15;
            s16x8 a0 = *(const s16x8*)(lds + r0*128 + ((kch << 4) ^ ((r0 & 7) << 4)));
            s16x8 a1 = *(const s16x8*)(lds + r1*128 + ((kch << 4) ^ ((r1 & 7) << 4)));
            #pragma unroll
            for (int nf = 0; nf < 8; nf++){
                int n = nf*16 + l15;
                s16x8 b = *(const s16x8*)(lds + 16384 + n*128 + ((kch << 4) ^ ((n & 7) << 4)));
                acc[0][nf] = __builtin_amdgcn_mfma_f32_16x16x32_bf16(a0, b, acc[0][nf], 0, 0, 0);
                acc[1][nf] = __builtin_amdgcn_mfma_f32_16x16x32_bf16(a1, b, acc[1][nf], 0, 0, 0);
            }
        }
        #pragma unroll
        for (int mi = 0; mi < 2; mi++)
        #pragma unroll
        for (int nf = 0; nf < 8; nf++){
            int ncol = nf*16 + l15;
            float b1 = fc_b1[layer*128 + ncol];
            #pragma unroll
            for (int q = 0; q < 4; q++){
                int mrow = w*32 + mi*16 + l4*4 + q;
                float hv = fmaxf(acc[mi][nf][q] + b1, 0.f);
                *(unsigned short*)(lds + 32768 + mrow*256 + (((ncol >> 3) << 4) ^ ((mrow & 7) << 4)) + (ncol & 7)*2) = f2bf(hv);
            }
        }
    }
    __syncthreads();
    // ---- head: f_out = h2.u + d ; forecast accumulate ----
    {
        int r = t >> 1, half = t & 1;
        const float* up = (const float*)((char*)ws_f + WSB_U) + layer*128 + half*64;
        float sum = 0.f;
        #pragma unroll
        for (int c = 0; c < 8; c++){
            int kch = half*8 + c;
            s16x8 hv = *(const s16x8*)(lds + 32768 + r*256 + ((kch << 4) ^ ((r & 7) << 4)));
            #pragma unroll
            for (int e = 0; e < 8; e++) sum += bf2f((unsigned short)hv[e]) * up[c*8 + e];
        }
        sum += __shfl_xor(sum, 1);
        if (half == 0){
            float fo = sum + *((const float*)((char*)ws_f + WSB_D) + layer);
            long g = slab*128 + r;
            if (first) out[g] = fo; else out[g] += fo;
        }
    }
}

// ============ host launch ============
extern "C" void kernel_launch(void* const* d_in, const int* in_sizes, int n_in,
                              void* d_out, int out_size, void* d_ws, size_t ws_size,
                              hipStream_t stream){
    if (ws_size < (size_t)WS_NEEDED) return;
    const float* xin    = (const float*)d_in[0];
    const float* in_w   = (const float*)d_in[1];
    const float* in_b   = (const float*)d_in[2];
    const float* fwy_re = (const float*)d_in[3];
    const float* fwy_im = (const float*)d_in[4];
    const float* fwx_re = (const float*)d_in[5];
    const float* fwx_im = (const float*)d_in[6];
    const float* bc_w1  = (const float*)d_in[7];
    const float* bc_b1  = (const float*)d_in[8];
    const float* bc_w2  = (const float*)d_in[9];
    const float* bc_b2  = (const float*)d_in[10];
    const float* fc_w1  = (const float*)d_in[11];
    const float* fc_b1  = (const float*)d_in[12];
    const float* fc_w2  = (const float*)d_in[13];
    const float* fc_b2  = (const float*)d_in[14];
    const float* out_w1 = (const float*)d_in[15];
    const float* out_b1 = (const float*)d_in[16];
    const float* out_w2 = (const float*)d_in[17];
    const float* out_b2 = (const float*)d_in[18];
    float* ws  = (float*)d_ws;
    float* out = (float*)d_out;

    k_init<<<1, 256, 0, stream>>>(out_w1, out_b1, out_w2, out_b2, fc_w2, fc_b2, ws);
    k_wconv<<<384, 256, 0, stream>>>(bc_w1, fc_w1, bc_w2, ws);
    k_wmix<<<2048, 256, 0, stream>>>(fwy_re, fwy_im, fwx_re, fwx_im, ws);
    k_embed<<<NPIX/4, 256, 0, stream>>>(xin, in_w, in_b, ws);

    for (int l = 0; l < NL; l++){
        k_spec_x<<<1024, 256, 0, stream>>>(ws, l);
        k_spec_y_ff<<<2048, 256, 0, stream>>>(ws, out, bc_b1, bc_b2, fc_b1, l, l == 0 ? 1 : 0);
    }
}